// Round 4
// baseline (143.480 us; speedup 1.0000x reference)
//
#include <hip/hip_runtime.h>

#define BATCH 4
#define NPTS 16384
#define NQ 2048
#define NFEAT 64
#define NS 32
#define NCH 67        // 3 + NFEAT
#define GRID 10       // cell edge 0.1 == radius
#define NCELL 1000
#define CSTRIDE 1024  // per-batch stride for cellStart
#define MAXHIT 128    // hit-list capacity per query (expected ~68 hits)

__device__ __forceinline__ int prefix_popc(unsigned long long m) {
  return (int)__builtin_amdgcn_mbcnt_hi(
      (unsigned)(m >> 32), __builtin_amdgcn_mbcnt_lo((unsigned)m, 0u));
}

__device__ __forceinline__ void cell3(float x, float y, float z, int& cx,
                                      int& cy, int& cz) {
  cx = min(max((int)(x * 10.0f), 0), GRID - 1);
  cy = min(max((int)(y * 10.0f), 0), GRID - 1);
  cz = min(max((int)(z * 10.0f), 0), GRID - 1);
}

// ---------------------------------------------------------------------------
// prep: blocks 0..3 build the per-batch cell grid entirely in LDS
// (hist -> scan -> scatter); blocks 4.. transpose features (B,C,N)->(B,N,C).
// LDS for the two roles is overlaid (16.6 KB) so transpose blocks keep
// 9 blocks/CU occupancy.
// ---------------------------------------------------------------------------
__global__ __launch_bounds__(1024) void prep_kernel(
    const float* __restrict__ xyz, const float* __restrict__ feat,
    float* __restrict__ featT, float4* __restrict__ cellPts,
    int* __restrict__ cellStart) {
  __shared__ float4 smem[64 * 65 / 4];  // 16.6 KB shared by both roles
  int* lhist = (int*)smem;              // [1024]
  int* lscan = lhist + 1024;            // [1024]
  int* lfill = lscan + 1024;            // [1024]  (12 KB <= 16.6 KB)
  float(*tile)[65] = (float(*)[65])smem;
  const int tid = threadIdx.x;

  if (blockIdx.x < BATCH) {
    // ----- grid build, one block per batch -----
    const int b = blockIdx.x;
    const float* xb = xyz + (size_t)b * NPTS * 3;
    lhist[tid] = 0;
    lfill[tid] = 0;
    __syncthreads();
#pragma unroll
    for (int c = 0; c < NPTS / 1024; c++) {
      const int i = c * 1024 + tid;
      const float x = xb[i * 3 + 0];
      const float y = xb[i * 3 + 1];
      const float z = xb[i * 3 + 2];
      int cx, cy, cz;
      cell3(x, y, z, cx, cy, cz);
      atomicAdd(&lhist[(cz * GRID + cy) * GRID + cx], 1);
    }
    __syncthreads();
    const int val = lhist[tid];
    lscan[tid] = val;
    __syncthreads();
    for (int d = 1; d < 1024; d <<= 1) {
      const int t2 = (tid >= d) ? lscan[tid - d] : 0;
      __syncthreads();
      lscan[tid] += t2;
      __syncthreads();
    }
    const int excl = lscan[tid] - val;  // exclusive prefix
    if (tid <= NCELL) cellStart[b * CSTRIDE + tid] = excl;  // [NCELL]==NPTS
    lhist[tid] = excl;  // reuse as per-cell start
    __syncthreads();
#pragma unroll
    for (int c = 0; c < NPTS / 1024; c++) {
      const int i = c * 1024 + tid;
      const float x = xb[i * 3 + 0];
      const float y = xb[i * 3 + 1];
      const float z = xb[i * 3 + 2];
      int cx, cy, cz;
      cell3(x, y, z, cx, cy, cz);
      const int cid = (cz * GRID + cy) * GRID + cx;
      const int pos = lhist[cid] + atomicAdd(&lfill[cid], 1);
      cellPts[(size_t)b * NPTS + pos] = make_float4(x, y, z, __int_as_float(i));
    }
  } else {
    // ----- transpose tile, 64x64, 1024 threads (one pass each way) -----
    const int t2 = blockIdx.x - BATCH;
    const int b = t2 >> 8;  // 256 tiles per batch
    const int n0 = (t2 & 255) * 64;
    const float* inb = feat + (size_t)b * NFEAT * NPTS;
    float* outb = featT + (size_t)b * NPTS * NFEAT;
    {
      const int c = tid >> 4;
      const int nq = (tid & 15) * 4;
      const float4 v = *(const float4*)&inb[(size_t)c * NPTS + n0 + nq];
      tile[c][nq + 0] = v.x;
      tile[c][nq + 1] = v.y;
      tile[c][nq + 2] = v.z;
      tile[c][nq + 3] = v.w;
    }
    __syncthreads();
    {
      const int n = tid >> 4;
      const int cq = (tid & 15) * 4;
      float4 v;
      v.x = tile[cq + 0][n];
      v.y = tile[cq + 1][n];
      v.z = tile[cq + 2][n];
      v.w = tile[cq + 3][n];
      *(float4*)&outb[(size_t)(n0 + n) * NFEAT + cq] = v;
    }
  }
}

// ---------------------------------------------------------------------------
// main: grid ball-query (scalar-preloaded bounds) + rank-selection +
// staged coalesced group. One wave per query, 4 waves per block.
// ---------------------------------------------------------------------------
__global__ __launch_bounds__(256) void qg_main(
    const float* __restrict__ xyz, const float* __restrict__ new_xyz,
    const float* __restrict__ featT, const float4* __restrict__ cellPts,
    const int* __restrict__ cellStart, float* __restrict__ out) {
  __shared__ int H[4][MAXHIT];
  __shared__ float Hx[4][MAXHIT], Hy[4][MAXHIT], Hz[4][MAXHIT];
  __shared__ int S[4][NS];
  __shared__ float F[4][35][33];  // pad 33: 2-way conflicts only (free)

  const int w = threadIdx.x >> 6;
  const int lane = threadIdx.x & 63;
  const int query = blockIdx.x * 4 + w;
  const int b = query >> 11;  // / NQ
  const int j = query & (NQ - 1);

  const float* q = new_xyz + ((size_t)b * NQ + j) * 3;
  const float qx = q[0], qy = q[1], qz = q[2];

  const float R2 = (float)(0.1 * 0.1);  // 0x3C23D70A — matches np exactly

  int cx, cy, cz;
  cell3(qx, qy, qz, cx, cy, cz);
  const int* cs = cellStart + b * CSTRIDE;
  const float4* cp = cellPts + (size_t)b * NPTS;

  // Init hit-list keys to +inf (slots never written stay MAX). Same-wave
  // ordering with later scan writes is guaranteed (one LDS pipe, in order).
  H[w][lane] = 0x7fffffff;
  H[w][lane + 64] = 0x7fffffff;

  // ---- preload all 9 segment bounds as scalar loads (one wait) ----
  const int cxm = max(cx - 1, 0);
  const int cxp = min(cx + 1, GRID - 1);
  int sArr[9], eArr[9];
#pragma unroll
  for (int r = 0; r < 9; r++) {
    const int dy = r % 3 - 1, dz = r / 3 - 1;
    const int cyy = cy + dy, czz = cz + dz;
    const bool ok = ((unsigned)cyy < GRID) && ((unsigned)czz < GRID);
    const int rowbase = (czz * GRID + cyy) * GRID;
    const int i0 = __builtin_amdgcn_readfirstlane(ok ? rowbase + cxm : 0);
    const int i1 = __builtin_amdgcn_readfirstlane(ok ? rowbase + cxp + 1 : 0);
    const int sv = cs[i0];
    const int ev = cs[i1];
    sArr[r] = ok ? sv : 0;
    eArr[r] = ok ? ev : 0;
  }

  // ---- collect all hits (index + coords) into per-wave LDS lists ----
  int count = 0;
#pragma unroll
  for (int r = 0; r < 9; r++) {
    const int s = sArr[r];
    const int e = eArr[r];
    for (int i = s + lane; i < e + 63; i += 64) {
      const float4 p = cp[min(i, NPTS - 1)];
      const float dxf = __fsub_rn(qx, p.x);
      const float dyf = __fsub_rn(qy, p.y);
      const float dzf = __fsub_rn(qz, p.z);
      const float d2 =
          __fadd_rn(__fadd_rn(__fmul_rn(dxf, dxf), __fmul_rn(dyf, dyf)),
                    __fmul_rn(dzf, dzf));
      const bool hit = (i < e) && (d2 < R2);
      const unsigned long long m = __ballot(hit);
      if (hit) {
        const int pos = count + prefix_popc(m);
        if (pos < MAXHIT) {
          H[w][pos] = (__float_as_int(p.w) << 7) | pos;  // key: idx|slot
          Hx[w][pos] = p.x;
          Hy[w][pos] = p.y;
          Hz[w][pos] = p.z;
        }
      }
      count += (int)__popcll(m);
    }
  }
  __syncthreads();  // A: H/Hx/Hy/Hz visible

  if (count <= MAXHIT) {
    // ---- rank selection: smallest 32 of up to 128 keys, no sort ----
    const int k0 = H[w][lane];
    const int k1 = H[w][lane + 64];
    const int4* Hv = (const int4*)&H[w][0];
    int r0 = 0, r1 = 0, mn = 0x7fffffff;
#pragma unroll
    for (int t = 0; t < MAXHIT / 4; t++) {
      const int4 h = Hv[t];  // broadcast read, conflict-free, pipelined
      mn = min(mn, min(min(h.x, h.y), min(h.z, h.w)));
      r0 += (h.x < k0) + (h.y < k0) + (h.z < k0) + (h.w < k0);
      r1 += (h.x < k1) + (h.y < k1) + (h.z < k1) + (h.w < k1);
    }
    // owners scatter their keys to their rank; pad slots get min key (first
    // hit) or 0 when there are no hits. Disjoint writes -> single phase.
    if (k0 != 0x7fffffff && r0 < NS) S[w][r0] = k0;
    if (k1 != 0x7fffffff && r1 < NS) S[w][r1] = k1;
    const int found = min(count, NS);
    if (lane >= found && lane < NS) S[w][lane] = (count > 0) ? mn : 0;
  } else {
    // ---- overflow fallback (P ~ 1e-10): exact ordered sequential scan ----
    const float* xb = xyz + (size_t)b * NPTS * 3;
    int cnt2 = 0;
    for (int base = 0; base < NPTS; base += 64) {
      const int i = base + lane;
      const float px = xb[i * 3 + 0];
      const float py = xb[i * 3 + 1];
      const float pz = xb[i * 3 + 2];
      const float dxf = __fsub_rn(qx, px);
      const float dyf = __fsub_rn(qy, py);
      const float dzf = __fsub_rn(qz, pz);
      const float d2 =
          __fadd_rn(__fadd_rn(__fmul_rn(dxf, dxf), __fmul_rn(dyf, dyf)),
                    __fmul_rn(dzf, dzf));
      const bool hit = d2 < R2;
      const unsigned long long m = __ballot(hit);
      if (hit) {
        const int pos = cnt2 + prefix_popc(m);
        if (pos < NS) {
          S[w][pos] = (i << 7) | pos;
          Hx[w][pos] = px;
          Hy[w][pos] = py;
          Hz[w][pos] = pz;
        }
      }
      cnt2 += (int)__popcll(m);
      if (cnt2 >= NS) break;
    }
    const int found = min(cnt2, NS);
    if (lane < NS && lane >= found) S[w][lane] = found ? S[w][0] : 0;
  }
  if (count == 0 && lane == 0) {  // no hits -> point 0 per reference
    const float* xb = xyz + (size_t)b * NPTS * 3;
    Hx[w][0] = xb[0];
    Hy[w][0] = xb[1];
    Hz[w][0] = xb[2];
  }
  __syncthreads();  // B: S (and no-hit coords) visible

  // ---- group phase: 2 passes of (gather -> LDS transpose -> float4 store) --
  const int r8 = lane >> 3;  // channel-in-group / row selector
  const int l8 = lane & 7;   // float4 slot / sample-quad
  const float* fb = featT + (size_t)b * NPTS * NFEAT;
  const size_t ob = ((size_t)b * NCH * NQ + j) * (size_t)NS;

  // pass 0: xyz (channels 0..2) + features 0..31 (channels 3..34)
  if (lane < NS) {
    const int packed = S[w][lane];
    const int pos = packed & (MAXHIT - 1);
    F[w][0][lane] = __fsub_rn(Hx[w][pos], qx);
    F[w][1][lane] = __fsub_rn(Hy[w][pos], qy);
    F[w][2][lane] = __fsub_rn(Hz[w][pos], qz);
  }
#pragma unroll
  for (int t = 0; t < 4; t++) {
    const int s = t * 8 + r8;
    const int gi = S[w][s] >> 7;
    const float4 v = *(const float4*)&fb[(size_t)gi * NFEAT + l8 * 4];
    F[w][3 + l8 * 4 + 0][s] = v.x;
    F[w][3 + l8 * 4 + 1][s] = v.y;
    F[w][3 + l8 * 4 + 2][s] = v.z;
    F[w][3 + l8 * 4 + 3][s] = v.w;
  }
  __syncthreads();  // C
#pragma unroll
  for (int c0 = 0; c0 < 35; c0 += 8) {
    const int c = c0 + r8;
    if (c < 35) {
      float4 v;
      v.x = F[w][c][l8 * 4 + 0];
      v.y = F[w][c][l8 * 4 + 1];
      v.z = F[w][c][l8 * 4 + 2];
      v.w = F[w][c][l8 * 4 + 3];
      *(float4*)&out[ob + (size_t)c * (NQ * NS) + l8 * 4] = v;
    }
  }
  __syncthreads();  // D (WAR: pass-1 overwrites F)

  // pass 1: features 32..63 (channels 35..66)
#pragma unroll
  for (int t = 0; t < 4; t++) {
    const int s = t * 8 + r8;
    const int gi = S[w][s] >> 7;
    const float4 v = *(const float4*)&fb[(size_t)gi * NFEAT + 32 + l8 * 4];
    F[w][l8 * 4 + 0][s] = v.x;
    F[w][l8 * 4 + 1][s] = v.y;
    F[w][l8 * 4 + 2][s] = v.z;
    F[w][l8 * 4 + 3][s] = v.w;
  }
  __syncthreads();  // E
#pragma unroll
  for (int c0 = 0; c0 < 32; c0 += 8) {
    const int r = c0 + r8;
    const int c = 35 + r;
    float4 v;
    v.x = F[w][r][l8 * 4 + 0];
    v.y = F[w][r][l8 * 4 + 1];
    v.z = F[w][r][l8 * 4 + 2];
    v.w = F[w][r][l8 * 4 + 3];
    *(float4*)&out[ob + (size_t)c * (NQ * NS) + l8 * 4] = v;
  }
}

// ---------------------------------------------------------------------------
// Fallback for tiny workspace: direct scan kernel (round-1, known-correct).
// ---------------------------------------------------------------------------
__global__ __launch_bounds__(256) void query_group_direct(
    const float* __restrict__ xyz, const float* __restrict__ new_xyz,
    const float* __restrict__ feat, float* __restrict__ out) {
  __shared__ int sidx[4][NS];
  const int w = threadIdx.x >> 6;
  const int lane = threadIdx.x & 63;
  const int query = blockIdx.x * 4 + w;
  const int b = query >> 11;
  const int j = query & (NQ - 1);
  const float* q = new_xyz + ((size_t)b * NQ + j) * 3;
  const float qx = q[0], qy = q[1], qz = q[2];
  const float* xb = xyz + (size_t)b * NPTS * 3;
  const float R2 = (float)(0.1 * 0.1);
  int count = 0;
  for (int base = 0; base < NPTS; base += 64) {
    const int i = base + lane;
    const float dx = __fsub_rn(qx, xb[i * 3 + 0]);
    const float dy = __fsub_rn(qy, xb[i * 3 + 1]);
    const float dz = __fsub_rn(qz, xb[i * 3 + 2]);
    const float d2 = __fadd_rn(
        __fadd_rn(__fmul_rn(dx, dx), __fmul_rn(dy, dy)), __fmul_rn(dz, dz));
    const bool hit = d2 < R2;
    const unsigned long long m = __ballot(hit);
    if (hit) {
      const int pos = count + prefix_popc(m);
      if (pos < NS) sidx[w][pos] = i;
    }
    count += (int)__popcll(m);
    if (count >= NS) break;
  }
  const int found = count < NS ? count : NS;
  const int fill = (found > 0) ? sidx[w][0] : 0;
  if (lane < NS && lane >= found) sidx[w][lane] = fill;
  const int k = lane & 31;
  const int half = lane >> 5;
  const int gi = sidx[w][k];
  const float px = xb[gi * 3 + 0], py = xb[gi * 3 + 1], pz = xb[gi * 3 + 2];
  const size_t obase = ((size_t)b * NCH * NQ + j) * (size_t)NS + k;
  for (int c = half; c < NCH; c += 2) {
    float v;
    if (c < 3) {
      v = (c == 0) ? __fsub_rn(px, qx)
                   : (c == 1) ? __fsub_rn(py, qy) : __fsub_rn(pz, qz);
    } else {
      v = feat[((size_t)b * NFEAT + (c - 3)) * NPTS + gi];
    }
    out[obase + (size_t)c * (NQ * NS)] = v;
  }
}

extern "C" void kernel_launch(void* const* d_in, const int* in_sizes, int n_in,
                              void* d_out, int out_size, void* d_ws,
                              size_t ws_size, hipStream_t stream) {
  const float* xyz     = (const float*)d_in[0];  // (B, N, 3)
  const float* new_xyz = (const float*)d_in[1];  // (B, NPOINT, 3)
  const float* feat    = (const float*)d_in[2];  // (B, C, N)
  float* out = (float*)d_out;                    // (B, 67, NPOINT, 32)

  const size_t szFeatT  = (size_t)BATCH * NPTS * NFEAT * sizeof(float);  // 16MB
  const size_t szCells  = (size_t)BATCH * NPTS * sizeof(float4);         // 1MB
  const size_t szCStart = (size_t)BATCH * CSTRIDE * sizeof(int);
  const size_t need = szFeatT + szCells + szCStart;

  const int nblocks = (BATCH * NQ) / 4;  // one wave per query

  if (ws_size >= need) {
    char* p = (char*)d_ws;
    float*  featT     = (float*)p;  p += szFeatT;
    float4* cellPts   = (float4*)p; p += szCells;
    int*    cellStart = (int*)p;

    prep_kernel<<<BATCH + BATCH * (NPTS / 64), 1024, 0, stream>>>(
        xyz, feat, featT, cellPts, cellStart);
    qg_main<<<nblocks, 256, 0, stream>>>(xyz, new_xyz, featT, cellPts,
                                         cellStart, out);
  } else {
    query_group_direct<<<nblocks, 256, 0, stream>>>(xyz, new_xyz, feat, out);
  }
}